// Round 7
// baseline (526.785 us; speedup 1.0000x reference)
//
#include <hip/hip_runtime.h>
#include <hip/hip_bf16.h>
#include <math.h>
#include <stdint.h>

typedef __attribute__((ext_vector_type(8))) short bf16x8_t;
typedef __attribute__((ext_vector_type(4))) float f32x4_t;

#define LOG2E 1.4426950408889634f
#define GLB(p) ((const __attribute__((address_space(1))) void*)(p))
#define LDS(p) ((__attribute__((address_space(3))) void*)(p))

__device__ __forceinline__ unsigned short f2bf(float f) {
    union { float f; unsigned int u; } v; v.f = f;
    unsigned int r = v.u + 0x7FFFu + ((v.u >> 16) & 1u);
    return (unsigned short)(r >> 16);
}

__device__ __forceinline__ float bf2f(unsigned short us) {
    union { unsigned int u; float f; } c; c.u = (unsigned int)us << 16; return c.f;
}

__device__ __forceinline__ unsigned int pack2bf(float a, float b) {
#if __has_builtin(__builtin_amdgcn_cvt_pk_bf16_f32)
    auto r = __builtin_amdgcn_cvt_pk_bf16_f32(a, b);
    unsigned int u;
    __builtin_memcpy(&u, &r, 4);
    return u;
#else
    return (unsigned int)f2bf(a) | ((unsigned int)f2bf(b) << 16);
#endif
}

__device__ __forceinline__ float fast_rcp(float x) {
#if __has_builtin(__builtin_amdgcn_rcpf)
    return __builtin_amdgcn_rcpf(x);
#else
    return 1.0f / x;
#endif
}

// single-instruction v_exp_f32 (bypasses OCML denorm-fixup path)
__device__ __forceinline__ float fexp2(float x) {
#if __has_builtin(__builtin_amdgcn_exp2f)
    return __builtin_amdgcn_exp2f(x);
#else
    return exp2f(x);
#endif
}

// gelu tanh-form: 0.5x(1+tanh(0.79788456(x+0.044715x^3))) = x*t/(t+1), t=e^{2 inner}
__device__ __forceinline__ float gelu_fast(float v) {
    float x2 = v * v;
    float inner = v * fmaf(0.0356774081f, x2, 0.7978845608f);
    inner = fminf(fmaxf(inner, -20.f), 20.f);
    float t = fexp2(inner * 2.8853900817779268f); // 2*log2(e)
    return v * t * fast_rcp(t + 1.0f);
}

// ---------------- fused cast fp32 -> bf16 for x, enc + mask4 prep ----------------
// mask4[b][t][l16][nt] = maskp[b*2048 + t*64 + nt*16 + l16] ? -1e10 : 0  (8192 floats)
__global__ void cast2_bf16_k(const float* __restrict__ inA, unsigned short* __restrict__ outA,
                             const float* __restrict__ inB, unsigned short* __restrict__ outB,
                             int n4, const int* __restrict__ maskp, float* __restrict__ mask4) {
    if (blockIdx.y == 2) {
        int i = blockIdx.x * blockDim.x + threadIdx.x;
        if (i < 8192) {
            int nt = i & 3, l16 = (i >> 2) & 15, t = (i >> 6) & 31, b = (i >> 11) & 1;
            mask4[i] = maskp[b * 2048 + t * 64 + nt * 16 + l16] ? -1e10f : 0.0f;
        }
        return;
    }
    const float* in = blockIdx.y ? inB : inA;
    unsigned short* out = blockIdx.y ? outB : outA;
    int i = blockIdx.x * blockDim.x + threadIdx.x;
    if (i < n4) {
        float4 v = ((const float4*)in)[i];
        ushort4 o;
        o.x = f2bf(v.x); o.y = f2bf(v.y); o.z = f2bf(v.z); o.w = f2bf(v.w);
        ((ushort4*)out)[i] = o;
    }
}

// ---------------- fused weight transpose+cast: all 8 weights in one dispatch ----------------
__global__ void transpose_all_k(const float* __restrict__ s0, const float* __restrict__ s1,
                                const float* __restrict__ s2, const float* __restrict__ s3,
                                const float* __restrict__ s4, const float* __restrict__ s5,
                                const float* __restrict__ s6, const float* __restrict__ s7,
                                unsigned short* __restrict__ d0, unsigned short* __restrict__ d1,
                                unsigned short* __restrict__ d2, unsigned short* __restrict__ d3,
                                unsigned short* __restrict__ d4, unsigned short* __restrict__ d5,
                                unsigned short* __restrict__ d6, unsigned short* __restrict__ d7) {
    __shared__ float tile[32][33];
    int idx = blockIdx.x;
    const float* W; unsigned short* Wt; int K, N, bx, by;
    if (idx < 6144) {
        int which = idx >> 10, t = idx & 1023;
        bx = t & 31; by = t >> 5; K = 1024; N = 1024;
        switch (which) {
            case 0: W = s0; Wt = d0; break;
            case 1: W = s1; Wt = d1; break;
            case 2: W = s2; Wt = d2; break;
            case 3: W = s3; Wt = d3; break;
            case 4: W = s4; Wt = d4; break;
            default: W = s5; Wt = d5; break;
        }
    } else if (idx < 10240) {
        int t = idx - 6144;
        bx = t & 127; by = t >> 7; K = 1024; N = 4096;
        W = s6; Wt = d6;
    } else {
        int t = idx - 10240;
        bx = t & 31; by = t >> 5; K = 4096; N = 1024;
        W = s7; Wt = d7;
    }
    int k0 = by * 32, n0 = bx * 32;
    int tx = threadIdx.x, ty = threadIdx.y; // 32 x 8
#pragma unroll
    for (int i = 0; i < 32; i += 8)
        tile[ty + i][tx] = W[(long)(k0 + ty + i) * N + n0 + tx];
    __syncthreads();
#pragma unroll
    for (int i = 0; i < 32; i += 8)
        Wt[(long)(n0 + ty + i) * K + k0 + tx] = f2bf(tile[tx][ty + i]);
}

// ---------------- GEMM (256 thr): BK=64, XOR-swizzled staging ----------
// Used only for ff1 (BN=128, grid 1024 = 4 blocks/CU — the m97-structure).
// EP: 2 = bias+gelu -> bf16
template <int EP, int BN>
__global__ __launch_bounds__(256) void gemm_k(const unsigned short* __restrict__ A,
                                              const unsigned short* __restrict__ Bt,
                                              void* __restrict__ outp,
                                              const float* __restrict__ bias,
                                              int M, int N, int K) {
    __shared__ __align__(16) unsigned short As[128 * 64];
    __shared__ __align__(16) unsigned short Bs[BN * 64];
    const int NT = BN / 32;
    const int BG = BN / 32;
    int tid = threadIdx.x;
    int wave = tid >> 6, lane = tid & 63;
    int wm = wave >> 1, wn = wave & 1;
    int quad = lane >> 4, l16 = lane & 15;
    int bm = blockIdx.y * 128, bn = blockIdx.x * BN;

    f32x4_t acc[4][NT] = {};

    int srow = tid >> 3;
    int sgrp = (tid & 7) ^ (srow & 7);
    const unsigned short* Ag[4];
#pragma unroll
    for (int i = 0; i < 4; i++)
        Ag[i] = A + (long)(bm + i * 32 + srow) * K + sgrp * 8;
    const unsigned short* Bg[BG];
#pragma unroll
    for (int i = 0; i < BG; i++)
        Bg[i] = Bt + (long)(bn + i * 32 + srow) * K + sgrp * 8;

    for (int k0 = 0; k0 < K; k0 += 64) {
        __syncthreads();
#pragma unroll
        for (int i = 0; i < 4; i++)
            __builtin_amdgcn_global_load_lds(GLB(Ag[i] + k0), LDS(As + i * 2048 + tid * 8), 16, 0, 0);
#pragma unroll
        for (int i = 0; i < BG; i++)
            __builtin_amdgcn_global_load_lds(GLB(Bg[i] + k0), LDS(Bs + i * 2048 + tid * 8), 16, 0, 0);
        __syncthreads();
#pragma unroll
        for (int kk = 0; kk < 2; kk++) {
            int xg = ((kk * 4 + quad) ^ (l16 & 7)) * 8;
            bf16x8_t af[4], bfr[NT];
#pragma unroll
            for (int t = 0; t < 4; t++)
                af[t] = *(const bf16x8_t*)(As + (wm * 64 + t * 16 + l16) * 64 + xg);
#pragma unroll
            for (int t = 0; t < NT; t++)
                bfr[t] = *(const bf16x8_t*)(Bs + (wn * (BN / 2) + t * 16 + l16) * 64 + xg);
#pragma unroll
            for (int mt = 0; mt < 4; mt++)
#pragma unroll
                for (int nt = 0; nt < NT; nt++)
                    acc[mt][nt] = __builtin_amdgcn_mfma_f32_16x16x32_bf16(af[mt], bfr[nt], acc[mt][nt], 0, 0, 0);
        }
    }

#pragma unroll
    for (int mt = 0; mt < 4; mt++)
#pragma unroll
        for (int nt = 0; nt < NT; nt++)
#pragma unroll
            for (int r = 0; r < 4; r++) {
                int gm = bm + wm * 64 + mt * 16 + quad * 4 + r;
                int gn = bn + wn * (BN / 2) + nt * 16 + l16;
                float v = acc[mt][nt][r];
                if (EP == 2) {
                    v = gelu_fast(v + bias[gn]);
                    ((unsigned short*)outp)[(long)gm * N + gn] = f2bf(v);
                } else {
                    ((unsigned short*)outp)[(long)gm * N + gn] = f2bf(v);
                }
            }
}

// ---------------- GEMM8 (512 thr): 128x128 tile, dbuf + counted vmcnt (T3+T4) ----------
// (exact R5 structure — measured best GEMM config, 490.7us total)
// EP: 4 = bf16, 6 = bias -> bf16,
//     7 = self-attn QK proj: cols [0,1024) -> Q head-split, [1024,2048) -> K + K^T perm
//     8 = cross-attn: z=0 -> Q head-split, z=1 -> K + K^T perm
template <int EP>
__global__ __launch_bounds__(512, 4) void gemm8_k(const unsigned short* __restrict__ A,
                                                  const unsigned short* __restrict__ Bt,
                                                  void* __restrict__ outp,
                                                  const float* __restrict__ bias,
                                                  const unsigned short* __restrict__ A2,
                                                  const unsigned short* __restrict__ Bt2,
                                                  unsigned short* __restrict__ qout,
                                                  unsigned short* __restrict__ kout,
                                                  unsigned short* __restrict__ ktout,
                                                  int M, int N, int K) {
    if (blockIdx.z) { A = A2; Bt = Bt2; }
    __shared__ __align__(16) unsigned short SMEM[32768]; // 64KB: As | Bs, reused as Ct
    unsigned short* As = SMEM;
    unsigned short* Bs = SMEM + 16384;
    int tid = threadIdx.x;
    int wave = tid >> 6, lane = tid & 63;
    int wm = wave >> 2, wn = wave & 3;   // 2 x 4 wave grid; wave tile 64 x 32
    int quad = lane >> 4, l16 = lane & 15;
    int bm = blockIdx.y * 128, bn = blockIdx.x * 128;

    f32x4_t acc[4][2] = {};

    int srow = tid >> 3;                 // 0..63
    int sgrp = (tid & 7) ^ (srow & 7);
    const unsigned short* Ag[2];
    const unsigned short* Bg[2];
#pragma unroll
    for (int i = 0; i < 2; i++) {
        Ag[i] = A + (long)(bm + i * 64 + srow) * K + sgrp * 8;
        Bg[i] = Bt + (long)(bn + i * 64 + srow) * K + sgrp * 8;
    }

    auto stage = [&](int buf, int k0) {
#pragma unroll
        for (int i = 0; i < 2; i++)
            __builtin_amdgcn_global_load_lds(GLB(Ag[i] + k0), LDS(As + buf * 8192 + i * 4096 + tid * 8), 16, 0, 0);
#pragma unroll
        for (int i = 0; i < 2; i++)
            __builtin_amdgcn_global_load_lds(GLB(Bg[i] + k0), LDS(Bs + buf * 8192 + i * 4096 + tid * 8), 16, 0, 0);
    };

    auto compute = [&](int buf) {
        const unsigned short* Ab = As + buf * 8192;
        const unsigned short* Bb = Bs + buf * 8192;
#pragma unroll
        for (int kk = 0; kk < 2; kk++) {
            int xg = ((kk * 4 + quad) ^ (l16 & 7)) * 8;
            bf16x8_t af[4], bfr[2];
#pragma unroll
            for (int t = 0; t < 4; t++)
                af[t] = *(const bf16x8_t*)(Ab + (wm * 64 + t * 16 + l16) * 64 + xg);
#pragma unroll
            for (int t = 0; t < 2; t++)
                bfr[t] = *(const bf16x8_t*)(Bb + (wn * 32 + t * 16 + l16) * 64 + xg);
#pragma unroll
            for (int mt = 0; mt < 4; mt++)
#pragma unroll
                for (int nt = 0; nt < 2; nt++)
                    acc[mt][nt] = __builtin_amdgcn_mfma_f32_16x16x32_bf16(af[mt], bfr[nt], acc[mt][nt], 0, 0, 0);
        }
    };

    stage(0, 0);
    const int NS = K >> 6;
    for (int i = 0; i < NS; i++) {
        if (i + 1 < NS) {
            stage((i + 1) & 1, (i + 1) << 6);  // next tile's 4 loads stay in flight
            asm volatile("s_waitcnt vmcnt(4)\n\ts_barrier" ::: "memory");
        } else {
            asm volatile("s_waitcnt vmcnt(0)\n\ts_barrier" ::: "memory");
        }
        compute(i & 1);
        asm volatile("s_barrier" ::: "memory");  // readers done before restage of this buf
    }

    if (EP == 7 || EP == 8) {
        // ---- fused head-split epilogue (replaces split_qk_k / transpose_heads_perm_k) ----
        bool kmode = (EP == 7) ? (bn >= 1024) : (blockIdx.z != 0);
        int G = (EP == 7 && kmode) ? ((bn - 1024) >> 7) : (bn >> 7);  // d-group 0..7
        unsigned short* Ct = SMEM;            // [128][132] bf16 output tile (33792B)
#pragma unroll
        for (int mt = 0; mt < 4; mt++)
#pragma unroll
            for (int nt = 0; nt < 2; nt++)
#pragma unroll
                for (int r = 0; r < 4; r++) {
                    int rr = wm * 64 + mt * 16 + quad * 4 + r;
                    int cc = wn * 32 + nt * 16 + l16;
                    Ct[rr * 132 + cc] = f2bf(acc[mt][nt][r]);
                }
        __syncthreads();
        int bq = bm >> 11;                    // batch (tiles never straddle 2048)
        if (!kmode) {
            // Q head-split: Qh[(b*16+h)][ll][ (G^sw)*8 + j ] = C[ll][(G*8+j)*16 + h]
#pragma unroll
            for (int i = 0; i < 4; i++) {
                int e = tid + i * 512;        // 2048 = 128 rows x 16 heads
                int h = e & 15, rl = e >> 4;
                int ll = (bm & 2047) + rl;
                union { uint4 v; unsigned short s[8]; } u;
#pragma unroll
                for (int j = 0; j < 8; j++) u.s[j] = Ct[rl * 132 + j * 16 + h];
                *(uint4*)(qout + (((long)(bq * 16 + h) * 2048 + ll) << 6) + ((G ^ (ll & 7)) << 3)) = u.v;
            }
        } else {
            // K head-split (same gather as Q)
#pragma unroll
            for (int i = 0; i < 4; i++) {
                int e = tid + i * 512;
                int h = e & 15, rl = e >> 4;
                int mm = (bm & 2047) + rl;
                union { uint4 v; unsigned short s[8]; } u;
#pragma unroll
                for (int j = 0; j < 8; j++) u.s[j] = Ct[rl * 132 + j * 16 + h];
                *(uint4*)(kout + (((long)(bq * 16 + h) * 2048 + mm) << 6) + ((G ^ (mm & 7)) << 3)) = u.v;
            }
            // K^T + m-perm: KhT[(b*16+h)*64+d][m0 + (glog^(d&7))*8 + j] = K[m0 + (p>>2)+(p&3)*16][d]
#pragma unroll
            for (int i = 0; i < 4; i++) {
                int e = tid + i * 512;        // 2048 = 16h x 8dl x 2m0s x 8glog
                int glog = e & 7, m0s = (e >> 3) & 1, dl = (e >> 4) & 7, h = e >> 7;
                int d = G * 8 + dl;
                union { uint4 v; unsigned short s[8]; } u;
#pragma unroll
                for (int j = 0; j < 8; j++) {
                    int p = glog * 8 + j;
                    int ml = (p >> 2) + (p & 3) * 16;
                    u.s[j] = Ct[(m0s * 64 + ml) * 132 + dl * 16 + h];
                }
                int mmbase = (bm & 2047) + m0s * 64;
                int gph = glog ^ (d & 7);
                *(uint4*)(ktout + ((long)(bq * 16 + h) * 64 + d) * 2048 + mmbase + gph * 8) = u.v;
            }
        }
        return;
    }

#pragma unroll
    for (int mt = 0; mt < 4; mt++)
#pragma unroll
        for (int nt = 0; nt < 2; nt++)
#pragma unroll
            for (int r = 0; r < 4; r++) {
                int gm = bm + wm * 64 + mt * 16 + quad * 4 + r;
                int gn = bn + wn * 32 + nt * 16 + l16;
                float v = acc[mt][nt][r];
                if (EP == 6) {
                    ((unsigned short*)outp)[(long)gm * N + gn] = f2bf(v + bias[gn]);
                } else {
                    ((unsigned short*)outp)[(long)gm * N + gn] = f2bf(v);
                }
            }
}

// ---------------- flash attention v9x: v9 + XCD-aware bh-grouping block swizzle ----------
// Each XCD owns 4 whole heads (bh) x all 32 l-tiles: the 512KB K/KhT stream per bh is
// fetched into ONE XCD's L2 (2MB working set, L2-resident) instead of all 8.
// Remap (bijective over 1024 blocks): o = by*32+bx; bh = (o&7) + 8*(o>>8); l-tile = (o>>3)&31.
template <int USE_MASK>
__global__ __launch_bounds__(256, 4) void flash_attn9_k(const unsigned short* __restrict__ Qh,
                                                        const unsigned short* __restrict__ Kh,
                                                        const unsigned short* __restrict__ KhTp,
                                                        const float* __restrict__ mask4,
                                                        unsigned short* __restrict__ out) {
    __shared__ __align__(16) unsigned short K1[64 * 64]; // [m][d] swizzled groups
    __shared__ __align__(16) unsigned short K2[64 * 64]; // [d][p] swizzled groups
    __shared__ __align__(16) unsigned short Ps[64 * 64]; // [l][p] XOR-8 row-swizzled
    __shared__ __align__(16) float Ml[USE_MASK ? 2048 : 4];

    int tid = threadIdx.x;
    int wave = tid >> 6, lane = tid & 63;
    int quad = lane >> 4, l16 = lane & 15;
    // XCD swizzle: group all l-tiles of a head onto one XCD
    int o = blockIdx.y * 32 + blockIdx.x;
    int bh = (o & 7) + ((o >> 8) << 3);
    int l0 = ((o >> 3) & 31) << 6;
    int b = bh >> 4, h = bh & 15;
    const unsigned short* k1p = Kh + (long)bh * 2048 * 64 + tid * 8;
    const unsigned short* k2p = KhTp + (long)bh * 64 * 2048 + (long)(tid >> 3) * 2048 + (tid & 7) * 8;

    int sw = l16 & 7;

    // Q fragments live in registers for the whole kernel (wave-invariant rows)
    const unsigned short* qrow = Qh + ((long)bh * 2048 + l0 + wave * 16 + l16) * 64;
    bf16x8_t qf[2];
#pragma unroll
    for (int kk = 0; kk < 2; kk++)
        qf[kk] = *(const bf16x8_t*)(qrow + ((kk * 4 + quad) ^ sw) * 8);

    // tile 0 staged via global_load_lds; __syncthreads drains it (once)
    __builtin_amdgcn_global_load_lds(GLB(k1p), LDS(K1 + tid * 8), 16, 0, 0);
    __builtin_amdgcn_global_load_lds(GLB(k1p + 2048), LDS(K1 + tid * 8 + 2048), 16, 0, 0);
    __builtin_amdgcn_global_load_lds(GLB(k2p), LDS(K2 + tid * 8), 16, 0, 0);
    __builtin_amdgcn_global_load_lds(GLB(k2p + 32 * 2048), LDS(K2 + tid * 8 + 2048), 16, 0, 0);
    if (USE_MASK) {
        const float* mp = mask4 + b * 2048;
        for (int c = tid; c < 512; c += 256)
            ((float4*)Ml)[c] = ((const float4*)mp)[c];
    }
    __syncthreads();

    const float C1 = 0.125f * LOG2E;
    f32x4_t acc_o[4] = {};
    float rs[4] = {0.f, 0.f, 0.f, 0.f};

    for (int t = 0; t < 32; ++t) {
        // T14 issue-early: next tile -> registers; latency hides under this tile's compute
        uint4 rA, rB, rC, rD;
        if (t < 31) {
            k1p += 4096;
            k2p += 64;
            rA = *(const uint4*)(k1p);
            rB = *(const uint4*)(k1p + 2048);
            rC = *(const uint4*)(k2p);
            rD = *(const uint4*)(k2p + 32 * 2048);
        }

        float4 mq = make_float4(0.f, 0.f, 0.f, 0.f);
        if (USE_MASK) mq = *(const float4*)(Ml + t * 64 + l16 * 4);

        // S = Q @ Ktile^T : wave handles 16 Q rows (band = wave*16), 64 m cols
        f32x4_t sacc[4] = {};
        __builtin_amdgcn_s_setprio(1);
#pragma unroll
        for (int kk = 0; kk < 2; kk++) {
            int xg = ((kk * 4 + quad) ^ sw) * 8;
#pragma unroll
            for (int nt = 0; nt < 4; nt++) {
                bf16x8_t bfr = *(const bf16x8_t*)(K1 + (nt * 16 + l16) * 64 + xg);
                sacc[nt] = __builtin_amdgcn_mfma_f32_16x16x32_bf16(qf[kk], bfr, sacc[nt], 0, 0, 0);
            }
        }
        __builtin_amdgcn_s_setprio(0);

        // p = exp2(s*C1 + mf); per-lane row-sum; write P 8B (4 bf16, permuted cols, swizzled)
#pragma unroll
        for (int r = 0; r < 4; r++) {
            float p0 = fexp2(fmaf(sacc[0][r], C1, mq.x));
            float p1 = fexp2(fmaf(sacc[1][r], C1, mq.y));
            float p2 = fexp2(fmaf(sacc[2][r], C1, mq.z));
            float p3 = fexp2(fmaf(sacc[3][r], C1, mq.w));
            rs[r] += (p0 + p1) + (p2 + p3);
            uint2 pk; pk.x = pack2bf(p0, p1); pk.y = pack2bf(p2, p3);
            int Rrow = wave * 16 + quad * 4 + r;
            int grp = (l16 >> 1) ^ (Rrow & 7);
            *(uint2*)(Ps + Rrow * 64 + grp * 8 + (l16 & 1) * 4) = pk;
        }

        // O += P @ Ktile : A = own band of Ps (wave-local, no barrier needed), B = K2
        __builtin_amdgcn_s_setprio(1);
#pragma unroll
        for (int kk = 0; kk < 2; kk++) {
            int xg = ((kk * 4 + quad) ^ sw) * 8;
            int Rr = wave * 16 + l16;
            int pg = ((kk * 4 + quad) ^ (l16 & 7)) * 8;
            bf16x8_t af = *(const bf16x8_t*)(Ps + Rr * 64 + pg);
#pragma unroll
            for (int nt = 0; nt < 4; nt++) {
                bf16x8_t bfr = *(const bf16x8_t*)(K2 + (nt * 16 + l16) * 64 + xg);
                acc_o[nt] = __builtin_amdgcn_mfma_f32_16x16x32_bf16(af, bfr, acc_o[nt], 0, 0, 0);
            }
        }
        __builtin_amdgcn_s_setprio(0);

        // write-late: all waves done reading K1/K2, then land the prefetched tile
        asm volatile("s_barrier" ::: "memory");
        if (t < 31) {
            *(uint4*)(K1 + tid * 8) = rA;            // compiler inserts vmcnt waits here
            *(uint4*)(K1 + tid * 8 + 2048) = rB;
            *(uint4*)(K2 + tid * 8) = rC;
            *(uint4*)(K2 + tid * 8 + 2048) = rD;
            asm volatile("s_waitcnt lgkmcnt(0)\n\ts_barrier" ::: "memory");
        }
    }

    // single final reduction of row sums across the 16 l16 lanes
#pragma unroll
    for (int r = 0; r < 4; r++) {
#pragma unroll
        for (int d = 1; d < 16; d <<= 1) rs[r] += __shfl_xor(rs[r], d);
    }

#pragma unroll
    for (int r = 0; r < 4; r++) {
        float inv = 1.0f / rs[r];
        int l = l0 + wave * 16 + quad * 4 + r;
#pragma unroll
        for (int nt = 0; nt < 4; nt++) {
            int d = nt * 16 + l16;
            out[((long)(b * 2048 + l)) * 1024 + d * 16 + h] = f2bf(acc_o[nt][r] * inv);
        }
    }
}

// ---------------- residual + layernorm ----------------
template <int AIN_BF16, int OUT_F32>
__global__ __launch_bounds__(256) void resid_ln_k(const void* __restrict__ ap,
                                                  const unsigned short* __restrict__ rb,
                                                  const float* __restrict__ g,
                                                  const float* __restrict__ bb,
                                                  float* __restrict__ outf,
                                                  unsigned short* __restrict__ outb) {
    long row = blockIdx.x;
    int tid = threadIdx.x;
    float x0, x1, x2, x3;
    if (AIN_BF16) {
        ushort4 va = ((const ushort4*)((const unsigned short*)ap + row * 1024))[tid];
        x0 = bf2f(va.x); x1 = bf2f(va.y); x2 = bf2f(va.z); x3 = bf2f(va.w);
    } else {
        float4 va = ((const float4*)((const float*)ap + row * 1024))[tid];
        x0 = va.x; x1 = va.y; x2 = va.z; x3 = va.w;
    }
    ushort4 vr = ((const ushort4*)(rb + row * 1024))[tid];
    x0 += bf2f(vr.x); x1 += bf2f(vr.y); x2 += bf2f(vr.z); x3 += bf2f(vr.w);
    float s = x0 + x1 + x2 + x3;
    float sq = x0 * x0 + x1 * x1 + x2 * x2 + x3 * x3;
#pragma unroll
    for (int d = 1; d < 64; d <<= 1) { s += __shfl_xor(s, d); sq += __shfl_xor(sq, d); }
    __shared__ float ss[4], ssq[4];
    int wave = tid >> 6, lane = tid & 63;
    if (lane == 0) { ss[wave] = s; ssq[wave] = sq; }
    __syncthreads();
    s = ss[0] + ss[1] + ss[2] + ss[3];
    sq = ssq[0] + ssq[1] + ssq[2] + ssq[3];
    float mean = s * (1.0f / 1024.0f);
    float var = sq * (1.0f / 1024.0f) - mean * mean;
    float rstd = rsqrtf(var + 1e-5f);
    float4 vg = ((const float4*)g)[tid];
    float4 vb = ((const float4*)bb)[tid];
    float y0 = (x0 - mean) * rstd * vg.x + vb.x;
    float y1 = (x1 - mean) * rstd * vg.y + vb.y;
    float y2 = (x2 - mean) * rstd * vg.z + vb.z;
    float y3 = (x3 - mean) * rstd * vg.w + vb.w;
    if (OUT_F32) {
        float4 o; o.x = y0; o.y = y1; o.z = y2; o.w = y3;
        ((float4*)(outf + row * 1024))[tid] = o;
    } else {
        ushort4 ob; ob.x = f2bf(y0); ob.y = f2bf(y1); ob.z = f2bf(y2); ob.w = f2bf(y3);
        ((ushort4*)(outb + row * 1024))[tid] = ob;
    }
}

extern "C" void kernel_launch(void* const* d_in, const int* in_sizes, int n_in,
                              void* d_out, int out_size, void* d_ws, size_t ws_size,
                              hipStream_t stream) {
    const float* x    = (const float*)d_in[0];
    const float* enc  = (const float*)d_in[1];
    const int*   mask = (const int*)d_in[2];
    const float* q1W  = (const float*)d_in[3];
    const float* w1W  = (const float*)d_in[4];
    const float* o1W  = (const float*)d_in[5];
    const float* q2W  = (const float*)d_in[6];
    const float* w2W  = (const float*)d_in[7];
    const float* o2W  = (const float*)d_in[8];
    const float* ffW1 = (const float*)d_in[9];
    const float* ffb1 = (const float*)d_in[10];
    const float* ffW2 = (const float*)d_in[11];
    const float* ffb2 = (const float*)d_in[12];
    const float* g1 = (const float*)d_in[13];
    const float* b1 = (const float*)d_in[14];
    const float* g2 = (const float*)d_in[15];
    const float* b2 = (const float*)d_in[16];
    const float* g3 = (const float*)d_in[17];
    const float* b3 = (const float*)d_in[18];
    float* outp = (float*)d_out;

    const int T = 4096;   // B*L
    const int D = 1024;
    const int F = 4096;   // MLP

    char* ws = (char*)d_ws;
    auto alloc = [&](size_t sz) { char* p = ws; ws += (sz + 255) & ~(size_t)255; return p; };
    unsigned short* qw1Wt = (unsigned short*)alloc((size_t)2 * D * D * 2); // fused [2048][1024]
    unsigned short* o1Wt  = (unsigned short*)alloc((size_t)D * D * 2);
    unsigned short* q2Wt  = (unsigned short*)alloc((size_t)D * D * 2);
    unsigned short* w2Wt  = (unsigned short*)alloc((size_t)D * D * 2);
    unsigned short* o2Wt  = (unsigned short*)alloc((size_t)D * D * 2);
    unsigned short* ffW1t = (unsigned short*)alloc((size_t)F * D * 2);
    unsigned short* ffW2t = (unsigned short*)alloc((size_t)D * F * 2);
    unsigned short* xb    = (unsigned short*)alloc((size_t)T * D * 2);
    unsigned short* encb  = (unsigned short*)alloc((size_t)T * D * 2);
    unsigned short* Qhb   = (unsigned short*)alloc((size_t)T * D * 2);
    unsigned short* Khb   = (unsigned short*)alloc((size_t)T * D * 2);
    unsigned short* KhTb  = (unsigned short*)alloc((size_t)T * D * 2);
    unsigned short* attnb = (unsigned short*)alloc((size_t)T * D * 2);
    float*          mask4b= (float*)alloc((size_t)8192 * 4);
    unsigned short* projb = (unsigned short*)alloc((size_t)T * D * 2);
    unsigned short* x1s   = (unsigned short*)alloc((size_t)T * D * 2);
    unsigned short* x2s   = (unsigned short*)alloc((size_t)T * D * 2);
    unsigned short* S1    = (unsigned short*)alloc((size_t)T * F * 2); // 32 MB scratch
    unsigned short* hb    = S1;                 // [4096][4096]

    dim3 blk256(256);
    dim3 blk512(512);
    dim3 tblk(32, 8);

    // prologue: fused casts (+ mask4 prep) + fused weight transposes
    cast2_bf16_k<<<dim3(T * D / 4 / 256, 3), blk256, 0, stream>>>(x, xb, enc, encb, T * D / 4, mask, mask4b);
    transpose_all_k<<<dim3(14336), tblk, 0, stream>>>(
        q1W, w1W, o1W, q2W, w2W, o2W, ffW1, ffW2,
        qw1Wt, qw1Wt + (size_t)D * D, o1Wt, q2Wt, w2Wt, o2Wt, ffW1t, ffW2t);

    // ---- self attention ----
    // qkv GEMM with fused head-split epilogue: writes Qhb, Khb, KhTb directly
    gemm8_k<7><<<dim3(2 * D / 128, T / 128, 1), blk512, 0, stream>>>(
        xb, qw1Wt, nullptr, nullptr, nullptr, nullptr, Qhb, Khb, KhTb, T, 2 * D, D);
    flash_attn9_k<0><<<dim3(32, 32), blk256, 0, stream>>>(Qhb, Khb, KhTb, nullptr, attnb);
    gemm8_k<4><<<dim3(D / 128, T / 128, 1), blk512, 0, stream>>>(
        attnb, o1Wt, projb, nullptr, nullptr, nullptr, nullptr, nullptr, nullptr, T, D, D);
    resid_ln_k<0, 0><<<dim3(T), blk256, 0, stream>>>(x, projb, g1, b1, nullptr, x1s);

    // ---- cross attention ----
    // q2 (z=0) -> Qhb head-split; w2 (z=1) -> Khb + KhTb
    gemm8_k<8><<<dim3(D / 128, T / 128, 2), blk512, 0, stream>>>(
        x1s, q2Wt, nullptr, nullptr, encb, w2Wt, Qhb, Khb, KhTb, T, D, D);
    flash_attn9_k<1><<<dim3(32, 32), blk256, 0, stream>>>(Qhb, Khb, KhTb, mask4b, attnb);
    gemm8_k<4><<<dim3(D / 128, T / 128, 1), blk512, 0, stream>>>(
        attnb, o2Wt, projb, nullptr, nullptr, nullptr, nullptr, nullptr, nullptr, T, D, D);
    resid_ln_k<1, 0><<<dim3(T), blk256, 0, stream>>>(x1s, projb, g2, b2, nullptr, x2s);

    // ---- feed forward ----
    gemm_k<2, 128><<<dim3(F / 128, T / 128, 1), blk256, 0, stream>>>(
        x2s, ffW1t, hb, ffb1, T, F, D);
    gemm8_k<6><<<dim3(D / 128, T / 128, 1), blk512, 0, stream>>>(
        hb, ffW2t, projb, ffb2, nullptr, nullptr, nullptr, nullptr, nullptr, T, D, F);
    resid_ln_k<1, 1><<<dim3(T), blk256, 0, stream>>>(x2s, projb, g3, b3, outp, nullptr);
}

// Round 8
// 482.654 us; speedup vs baseline: 1.0914x; 1.0914x over previous
//
#include <hip/hip_runtime.h>
#include <hip/hip_bf16.h>
#include <math.h>
#include <stdint.h>

typedef __attribute__((ext_vector_type(8))) short bf16x8_t;
typedef __attribute__((ext_vector_type(4))) float f32x4_t;

#define LOG2E 1.4426950408889634f
#define GLB(p) ((const __attribute__((address_space(1))) void*)(p))
#define LDS(p) ((__attribute__((address_space(3))) void*)(p))

__device__ __forceinline__ unsigned short f2bf(float f) {
    union { float f; unsigned int u; } v; v.f = f;
    unsigned int r = v.u + 0x7FFFu + ((v.u >> 16) & 1u);
    return (unsigned short)(r >> 16);
}

__device__ __forceinline__ float bf2f(unsigned short us) {
    union { unsigned int u; float f; } c; c.u = (unsigned int)us << 16; return c.f;
}

__device__ __forceinline__ unsigned int pack2bf(float a, float b) {
#if __has_builtin(__builtin_amdgcn_cvt_pk_bf16_f32)
    auto r = __builtin_amdgcn_cvt_pk_bf16_f32(a, b);
    unsigned int u;
    __builtin_memcpy(&u, &r, 4);
    return u;
#else
    return (unsigned int)f2bf(a) | ((unsigned int)f2bf(b) << 16);
#endif
}

__device__ __forceinline__ float fast_rcp(float x) {
#if __has_builtin(__builtin_amdgcn_rcpf)
    return __builtin_amdgcn_rcpf(x);
#else
    return 1.0f / x;
#endif
}

// single-instruction v_exp_f32 (bypasses OCML denorm-fixup path)
__device__ __forceinline__ float fexp2(float x) {
#if __has_builtin(__builtin_amdgcn_exp2f)
    return __builtin_amdgcn_exp2f(x);
#else
    return exp2f(x);
#endif
}

// gelu tanh-form: 0.5x(1+tanh(0.79788456(x+0.044715x^3))) = x*t/(t+1), t=e^{2 inner}
__device__ __forceinline__ float gelu_fast(float v) {
    float x2 = v * v;
    float inner = v * fmaf(0.0356774081f, x2, 0.7978845608f);
    inner = fminf(fmaxf(inner, -20.f), 20.f);
    float t = fexp2(inner * 2.8853900817779268f); // 2*log2(e)
    return v * t * fast_rcp(t + 1.0f);
}

// ---------------- fused cast fp32 -> bf16 for x, enc + mask4 prep ----------------
// mask4[b][t][l16][nt] = maskp[b*2048 + t*64 + nt*16 + l16] ? -1e10 : 0  (8192 floats)
__global__ void cast2_bf16_k(const float* __restrict__ inA, unsigned short* __restrict__ outA,
                             const float* __restrict__ inB, unsigned short* __restrict__ outB,
                             int n4, const int* __restrict__ maskp, float* __restrict__ mask4) {
    if (blockIdx.y == 2) {
        int i = blockIdx.x * blockDim.x + threadIdx.x;
        if (i < 8192) {
            int nt = i & 3, l16 = (i >> 2) & 15, t = (i >> 6) & 31, b = (i >> 11) & 1;
            mask4[i] = maskp[b * 2048 + t * 64 + nt * 16 + l16] ? -1e10f : 0.0f;
        }
        return;
    }
    const float* in = blockIdx.y ? inB : inA;
    unsigned short* out = blockIdx.y ? outB : outA;
    int i = blockIdx.x * blockDim.x + threadIdx.x;
    if (i < n4) {
        float4 v = ((const float4*)in)[i];
        ushort4 o;
        o.x = f2bf(v.x); o.y = f2bf(v.y); o.z = f2bf(v.z); o.w = f2bf(v.w);
        ((ushort4*)out)[i] = o;
    }
}

// ---------------- fused weight transpose+cast: all 8 weights in one dispatch ----------------
// o1W (which==2) and o2W (which==5) get a K-permutation: Wt[n][h*64+d] = W[d*16+h][n]
// (matches flash attn's head-contiguous output layout; permuted READ rows, coalesced writes)
__global__ void transpose_all_k(const float* __restrict__ s0, const float* __restrict__ s1,
                                const float* __restrict__ s2, const float* __restrict__ s3,
                                const float* __restrict__ s4, const float* __restrict__ s5,
                                const float* __restrict__ s6, const float* __restrict__ s7,
                                unsigned short* __restrict__ d0, unsigned short* __restrict__ d1,
                                unsigned short* __restrict__ d2, unsigned short* __restrict__ d3,
                                unsigned short* __restrict__ d4, unsigned short* __restrict__ d5,
                                unsigned short* __restrict__ d6, unsigned short* __restrict__ d7) {
    __shared__ float tile[32][33];
    int idx = blockIdx.x;
    const float* W; unsigned short* Wt; int K, N, bx, by;
    bool permK = false;
    if (idx < 6144) {
        int which = idx >> 10, t = idx & 1023;
        bx = t & 31; by = t >> 5; K = 1024; N = 1024;
        switch (which) {
            case 0: W = s0; Wt = d0; break;
            case 1: W = s1; Wt = d1; break;
            case 2: W = s2; Wt = d2; permK = true; break;
            case 3: W = s3; Wt = d3; break;
            case 4: W = s4; Wt = d4; break;
            default: W = s5; Wt = d5; permK = true; break;
        }
    } else if (idx < 10240) {
        int t = idx - 6144;
        bx = t & 127; by = t >> 7; K = 1024; N = 4096;
        W = s6; Wt = d6;
    } else {
        int t = idx - 10240;
        bx = t & 31; by = t >> 5; K = 4096; N = 1024;
        W = s7; Wt = d7;
    }
    int k0 = by * 32, n0 = bx * 32;
    int tx = threadIdx.x, ty = threadIdx.y; // 32 x 8
#pragma unroll
    for (int i = 0; i < 32; i += 8) {
        int kr = k0 + ty + i;
        int srcr = permK ? ((kr & 63) * 16 + (kr >> 6)) : kr;  // invperm: k'=h*64+d -> d*16+h
        tile[ty + i][tx] = W[(long)srcr * N + n0 + tx];
    }
    __syncthreads();
#pragma unroll
    for (int i = 0; i < 32; i += 8)
        Wt[(long)(n0 + ty + i) * K + k0 + tx] = f2bf(tile[tx][ty + i]);
}

// ---------------- GEMM (256 thr): BK=64, XOR-swizzled staging ----------
// Used only for ff1 (BN=128, grid 1024 = 4 blocks/CU — the m97-structure).
// EP: 2 = bias+gelu -> bf16
template <int EP, int BN>
__global__ __launch_bounds__(256) void gemm_k(const unsigned short* __restrict__ A,
                                              const unsigned short* __restrict__ Bt,
                                              void* __restrict__ outp,
                                              const float* __restrict__ bias,
                                              int M, int N, int K) {
    __shared__ __align__(16) unsigned short As[128 * 64];
    __shared__ __align__(16) unsigned short Bs[BN * 64];
    const int NT = BN / 32;
    const int BG = BN / 32;
    int tid = threadIdx.x;
    int wave = tid >> 6, lane = tid & 63;
    int wm = wave >> 1, wn = wave & 1;
    int quad = lane >> 4, l16 = lane & 15;
    int bm = blockIdx.y * 128, bn = blockIdx.x * BN;

    f32x4_t acc[4][NT] = {};

    int srow = tid >> 3;
    int sgrp = (tid & 7) ^ (srow & 7);
    const unsigned short* Ag[4];
#pragma unroll
    for (int i = 0; i < 4; i++)
        Ag[i] = A + (long)(bm + i * 32 + srow) * K + sgrp * 8;
    const unsigned short* Bg[BG];
#pragma unroll
    for (int i = 0; i < BG; i++)
        Bg[i] = Bt + (long)(bn + i * 32 + srow) * K + sgrp * 8;

    for (int k0 = 0; k0 < K; k0 += 64) {
        __syncthreads();
#pragma unroll
        for (int i = 0; i < 4; i++)
            __builtin_amdgcn_global_load_lds(GLB(Ag[i] + k0), LDS(As + i * 2048 + tid * 8), 16, 0, 0);
#pragma unroll
        for (int i = 0; i < BG; i++)
            __builtin_amdgcn_global_load_lds(GLB(Bg[i] + k0), LDS(Bs + i * 2048 + tid * 8), 16, 0, 0);
        __syncthreads();
#pragma unroll
        for (int kk = 0; kk < 2; kk++) {
            int xg = ((kk * 4 + quad) ^ (l16 & 7)) * 8;
            bf16x8_t af[4], bfr[NT];
#pragma unroll
            for (int t = 0; t < 4; t++)
                af[t] = *(const bf16x8_t*)(As + (wm * 64 + t * 16 + l16) * 64 + xg);
#pragma unroll
            for (int t = 0; t < NT; t++)
                bfr[t] = *(const bf16x8_t*)(Bs + (wn * (BN / 2) + t * 16 + l16) * 64 + xg);
#pragma unroll
            for (int mt = 0; mt < 4; mt++)
#pragma unroll
                for (int nt = 0; nt < NT; nt++)
                    acc[mt][nt] = __builtin_amdgcn_mfma_f32_16x16x32_bf16(af[mt], bfr[nt], acc[mt][nt], 0, 0, 0);
        }
    }

#pragma unroll
    for (int mt = 0; mt < 4; mt++)
#pragma unroll
        for (int nt = 0; nt < NT; nt++)
#pragma unroll
            for (int r = 0; r < 4; r++) {
                int gm = bm + wm * 64 + mt * 16 + quad * 4 + r;
                int gn = bn + wn * (BN / 2) + nt * 16 + l16;
                float v = acc[mt][nt][r];
                if (EP == 2) {
                    v = gelu_fast(v + bias[gn]);
                    ((unsigned short*)outp)[(long)gm * N + gn] = f2bf(v);
                } else {
                    ((unsigned short*)outp)[(long)gm * N + gn] = f2bf(v);
                }
            }
}

// ---------------- GEMM8 (512 thr): 128x128 tile, dbuf + counted vmcnt (T3+T4) ----------
// (exact R5 structure — measured best GEMM config, 490.7us total)
// EP: 4 = bf16, 6 = bias -> bf16,
//     7 = self-attn QK proj: cols [0,1024) -> Q head-split, [1024,2048) -> K + K^T perm
//     8 = cross-attn: z=0 -> Q head-split, z=1 -> K + K^T perm
template <int EP>
__global__ __launch_bounds__(512, 4) void gemm8_k(const unsigned short* __restrict__ A,
                                                  const unsigned short* __restrict__ Bt,
                                                  void* __restrict__ outp,
                                                  const float* __restrict__ bias,
                                                  const unsigned short* __restrict__ A2,
                                                  const unsigned short* __restrict__ Bt2,
                                                  unsigned short* __restrict__ qout,
                                                  unsigned short* __restrict__ kout,
                                                  unsigned short* __restrict__ ktout,
                                                  int M, int N, int K) {
    if (blockIdx.z) { A = A2; Bt = Bt2; }
    __shared__ __align__(16) unsigned short SMEM[32768]; // 64KB: As | Bs, reused as Ct
    unsigned short* As = SMEM;
    unsigned short* Bs = SMEM + 16384;
    int tid = threadIdx.x;
    int wave = tid >> 6, lane = tid & 63;
    int wm = wave >> 2, wn = wave & 3;   // 2 x 4 wave grid; wave tile 64 x 32
    int quad = lane >> 4, l16 = lane & 15;
    int bm = blockIdx.y * 128, bn = blockIdx.x * 128;

    f32x4_t acc[4][2] = {};

    int srow = tid >> 3;                 // 0..63
    int sgrp = (tid & 7) ^ (srow & 7);
    const unsigned short* Ag[2];
    const unsigned short* Bg[2];
#pragma unroll
    for (int i = 0; i < 2; i++) {
        Ag[i] = A + (long)(bm + i * 64 + srow) * K + sgrp * 8;
        Bg[i] = Bt + (long)(bn + i * 64 + srow) * K + sgrp * 8;
    }

    auto stage = [&](int buf, int k0) {
#pragma unroll
        for (int i = 0; i < 2; i++)
            __builtin_amdgcn_global_load_lds(GLB(Ag[i] + k0), LDS(As + buf * 8192 + i * 4096 + tid * 8), 16, 0, 0);
#pragma unroll
        for (int i = 0; i < 2; i++)
            __builtin_amdgcn_global_load_lds(GLB(Bg[i] + k0), LDS(Bs + buf * 8192 + i * 4096 + tid * 8), 16, 0, 0);
    };

    auto compute = [&](int buf) {
        const unsigned short* Ab = As + buf * 8192;
        const unsigned short* Bb = Bs + buf * 8192;
#pragma unroll
        for (int kk = 0; kk < 2; kk++) {
            int xg = ((kk * 4 + quad) ^ (l16 & 7)) * 8;
            bf16x8_t af[4], bfr[2];
#pragma unroll
            for (int t = 0; t < 4; t++)
                af[t] = *(const bf16x8_t*)(Ab + (wm * 64 + t * 16 + l16) * 64 + xg);
#pragma unroll
            for (int t = 0; t < 2; t++)
                bfr[t] = *(const bf16x8_t*)(Bb + (wn * 32 + t * 16 + l16) * 64 + xg);
#pragma unroll
            for (int mt = 0; mt < 4; mt++)
#pragma unroll
                for (int nt = 0; nt < 2; nt++)
                    acc[mt][nt] = __builtin_amdgcn_mfma_f32_16x16x32_bf16(af[mt], bfr[nt], acc[mt][nt], 0, 0, 0);
        }
    };

    stage(0, 0);
    const int NS = K >> 6;
    for (int i = 0; i < NS; i++) {
        if (i + 1 < NS) {
            stage((i + 1) & 1, (i + 1) << 6);  // next tile's 4 loads stay in flight
            asm volatile("s_waitcnt vmcnt(4)\n\ts_barrier" ::: "memory");
        } else {
            asm volatile("s_waitcnt vmcnt(0)\n\ts_barrier" ::: "memory");
        }
        compute(i & 1);
        asm volatile("s_barrier" ::: "memory");  // readers done before restage of this buf
    }

    if (EP == 7 || EP == 8) {
        // ---- fused head-split epilogue (replaces split_qk_k / transpose_heads_perm_k) ----
        bool kmode = (EP == 7) ? (bn >= 1024) : (blockIdx.z != 0);
        int G = (EP == 7 && kmode) ? ((bn - 1024) >> 7) : (bn >> 7);  // d-group 0..7
        unsigned short* Ct = SMEM;            // [128][132] bf16 output tile (33792B)
#pragma unroll
        for (int mt = 0; mt < 4; mt++)
#pragma unroll
            for (int nt = 0; nt < 2; nt++)
#pragma unroll
                for (int r = 0; r < 4; r++) {
                    int rr = wm * 64 + mt * 16 + quad * 4 + r;
                    int cc = wn * 32 + nt * 16 + l16;
                    Ct[rr * 132 + cc] = f2bf(acc[mt][nt][r]);
                }
        __syncthreads();
        int bq = bm >> 11;                    // batch (tiles never straddle 2048)
        if (!kmode) {
            // Q head-split: Qh[(b*16+h)][ll][ (G^sw)*8 + j ] = C[ll][(G*8+j)*16 + h]
#pragma unroll
            for (int i = 0; i < 4; i++) {
                int e = tid + i * 512;        // 2048 = 128 rows x 16 heads
                int h = e & 15, rl = e >> 4;
                int ll = (bm & 2047) + rl;
                union { uint4 v; unsigned short s[8]; } u;
#pragma unroll
                for (int j = 0; j < 8; j++) u.s[j] = Ct[rl * 132 + j * 16 + h];
                *(uint4*)(qout + (((long)(bq * 16 + h) * 2048 + ll) << 6) + ((G ^ (ll & 7)) << 3)) = u.v;
            }
        } else {
            // K head-split (same gather as Q)
#pragma unroll
            for (int i = 0; i < 4; i++) {
                int e = tid + i * 512;
                int h = e & 15, rl = e >> 4;
                int mm = (bm & 2047) + rl;
                union { uint4 v; unsigned short s[8]; } u;
#pragma unroll
                for (int j = 0; j < 8; j++) u.s[j] = Ct[rl * 132 + j * 16 + h];
                *(uint4*)(kout + (((long)(bq * 16 + h) * 2048 + mm) << 6) + ((G ^ (mm & 7)) << 3)) = u.v;
            }
            // K^T + m-perm: KhT[(b*16+h)*64+d][m0 + (glog^(d&7))*8 + j] = K[m0 + (p>>2)+(p&3)*16][d]
#pragma unroll
            for (int i = 0; i < 4; i++) {
                int e = tid + i * 512;        // 2048 = 16h x 8dl x 2m0s x 8glog
                int glog = e & 7, m0s = (e >> 3) & 1, dl = (e >> 4) & 7, h = e >> 7;
                int d = G * 8 + dl;
                union { uint4 v; unsigned short s[8]; } u;
#pragma unroll
                for (int j = 0; j < 8; j++) {
                    int p = glog * 8 + j;
                    int ml = (p >> 2) + (p & 3) * 16;
                    u.s[j] = Ct[(m0s * 64 + ml) * 132 + dl * 16 + h];
                }
                int mmbase = (bm & 2047) + m0s * 64;
                int gph = glog ^ (d & 7);
                *(uint4*)(ktout + ((long)(bq * 16 + h) * 64 + d) * 2048 + mmbase + gph * 8) = u.v;
            }
        }
        return;
    }

#pragma unroll
    for (int mt = 0; mt < 4; mt++)
#pragma unroll
        for (int nt = 0; nt < 2; nt++)
#pragma unroll
            for (int r = 0; r < 4; r++) {
                int gm = bm + wm * 64 + mt * 16 + quad * 4 + r;
                int gn = bn + wn * 32 + nt * 16 + l16;
                float v = acc[mt][nt][r];
                if (EP == 6) {
                    ((unsigned short*)outp)[(long)gm * N + gn] = f2bf(v + bias[gn]);
                } else {
                    ((unsigned short*)outp)[(long)gm * N + gn] = f2bf(v);
                }
            }
}

// ---------------- flash attention v11: XCD bh-grouping + head-contiguous output ----------
// Each XCD owns 4 whole heads (bh) x all 32 l-tiles -> K stream L2-resident (~12MB fetch).
// Output layout [b][l][h*64+d]: each block writes its own FULL 128B lines (contiguous
// 64 shorts per row) -> no cross-block write merging needed, no partial-line writeback.
// o1Wt/o2Wt rows are permuted to match (see transpose_all_k permK).
template <int USE_MASK>
__global__ __launch_bounds__(256, 4) void flash_attn11_k(const unsigned short* __restrict__ Qh,
                                                         const unsigned short* __restrict__ Kh,
                                                         const unsigned short* __restrict__ KhTp,
                                                         const float* __restrict__ mask4,
                                                         unsigned short* __restrict__ out) {
    __shared__ __align__(16) unsigned short K1[64 * 64]; // [m][d] swizzled groups
    __shared__ __align__(16) unsigned short K2[64 * 64]; // [d][p] swizzled groups
    __shared__ __align__(16) unsigned short Ps[64 * 64]; // [l][p] XOR-8 row-swizzled
    __shared__ __align__(16) float Ml[USE_MASK ? 2048 : 4];

    int tid = threadIdx.x;
    int wave = tid >> 6, lane = tid & 63;
    int quad = lane >> 4, l16 = lane & 15;
    // XCD swizzle: group all l-tiles of a head onto one XCD
    int o = blockIdx.y * 32 + blockIdx.x;
    int bh = (o & 7) + ((o >> 8) << 3);
    int l0 = ((o >> 3) & 31) << 6;
    int b = bh >> 4, h = bh & 15;
    const unsigned short* k1p = Kh + (long)bh * 2048 * 64 + tid * 8;
    const unsigned short* k2p = KhTp + (long)bh * 64 * 2048 + (long)(tid >> 3) * 2048 + (tid & 7) * 8;

    int sw = l16 & 7;

    // Q fragments live in registers for the whole kernel (wave-invariant rows)
    const unsigned short* qrow = Qh + ((long)bh * 2048 + l0 + wave * 16 + l16) * 64;
    bf16x8_t qf[2];
#pragma unroll
    for (int kk = 0; kk < 2; kk++)
        qf[kk] = *(const bf16x8_t*)(qrow + ((kk * 4 + quad) ^ sw) * 8);

    // tile 0 staged via global_load_lds; __syncthreads drains it (once)
    __builtin_amdgcn_global_load_lds(GLB(k1p), LDS(K1 + tid * 8), 16, 0, 0);
    __builtin_amdgcn_global_load_lds(GLB(k1p + 2048), LDS(K1 + tid * 8 + 2048), 16, 0, 0);
    __builtin_amdgcn_global_load_lds(GLB(k2p), LDS(K2 + tid * 8), 16, 0, 0);
    __builtin_amdgcn_global_load_lds(GLB(k2p + 32 * 2048), LDS(K2 + tid * 8 + 2048), 16, 0, 0);
    if (USE_MASK) {
        const float* mp = mask4 + b * 2048;
        for (int c = tid; c < 512; c += 256)
            ((float4*)Ml)[c] = ((const float4*)mp)[c];
    }
    __syncthreads();

    const float C1 = 0.125f * LOG2E;
    f32x4_t acc_o[4] = {};
    float rs[4] = {0.f, 0.f, 0.f, 0.f};

    for (int t = 0; t < 32; ++t) {
        // T14 issue-early: next tile -> registers; latency hides under this tile's compute
        uint4 rA, rB, rC, rD;
        if (t < 31) {
            k1p += 4096;
            k2p += 64;
            rA = *(const uint4*)(k1p);
            rB = *(const uint4*)(k1p + 2048);
            rC = *(const uint4*)(k2p);
            rD = *(const uint4*)(k2p + 32 * 2048);
        }

        float4 mq = make_float4(0.f, 0.f, 0.f, 0.f);
        if (USE_MASK) mq = *(const float4*)(Ml + t * 64 + l16 * 4);

        // S = Q @ Ktile^T : wave handles 16 Q rows (band = wave*16), 64 m cols
        f32x4_t sacc[4] = {};
        __builtin_amdgcn_s_setprio(1);
#pragma unroll
        for (int kk = 0; kk < 2; kk++) {
            int xg = ((kk * 4 + quad) ^ sw) * 8;
#pragma unroll
            for (int nt = 0; nt < 4; nt++) {
                bf16x8_t bfr = *(const bf16x8_t*)(K1 + (nt * 16 + l16) * 64 + xg);
                sacc[nt] = __builtin_amdgcn_mfma_f32_16x16x32_bf16(qf[kk], bfr, sacc[nt], 0, 0, 0);
            }
        }
        __builtin_amdgcn_s_setprio(0);

        // p = exp2(s*C1 + mf); per-lane row-sum; write P 8B (4 bf16, permuted cols, swizzled)
#pragma unroll
        for (int r = 0; r < 4; r++) {
            float p0 = fexp2(fmaf(sacc[0][r], C1, mq.x));
            float p1 = fexp2(fmaf(sacc[1][r], C1, mq.y));
            float p2 = fexp2(fmaf(sacc[2][r], C1, mq.z));
            float p3 = fexp2(fmaf(sacc[3][r], C1, mq.w));
            rs[r] += (p0 + p1) + (p2 + p3);
            uint2 pk; pk.x = pack2bf(p0, p1); pk.y = pack2bf(p2, p3);
            int Rrow = wave * 16 + quad * 4 + r;
            int grp = (l16 >> 1) ^ (Rrow & 7);
            *(uint2*)(Ps + Rrow * 64 + grp * 8 + (l16 & 1) * 4) = pk;
        }

        // O += P @ Ktile : A = own band of Ps (wave-local, no barrier needed), B = K2
        __builtin_amdgcn_s_setprio(1);
#pragma unroll
        for (int kk = 0; kk < 2; kk++) {
            int xg = ((kk * 4 + quad) ^ sw) * 8;
            int Rr = wave * 16 + l16;
            int pg = ((kk * 4 + quad) ^ (l16 & 7)) * 8;
            bf16x8_t af = *(const bf16x8_t*)(Ps + Rr * 64 + pg);
#pragma unroll
            for (int nt = 0; nt < 4; nt++) {
                bf16x8_t bfr = *(const bf16x8_t*)(K2 + (nt * 16 + l16) * 64 + xg);
                acc_o[nt] = __builtin_amdgcn_mfma_f32_16x16x32_bf16(af, bfr, acc_o[nt], 0, 0, 0);
            }
        }
        __builtin_amdgcn_s_setprio(0);

        // write-late: all waves done reading K1/K2, then land the prefetched tile
        asm volatile("s_barrier" ::: "memory");
        if (t < 31) {
            *(uint4*)(K1 + tid * 8) = rA;            // compiler inserts vmcnt waits here
            *(uint4*)(K1 + tid * 8 + 2048) = rB;
            *(uint4*)(K2 + tid * 8) = rC;
            *(uint4*)(K2 + tid * 8 + 2048) = rD;
            asm volatile("s_waitcnt lgkmcnt(0)\n\ts_barrier" ::: "memory");
        }
    }

    // single final reduction of row sums across the 16 l16 lanes
#pragma unroll
    for (int r = 0; r < 4; r++) {
#pragma unroll
        for (int d = 1; d < 16; d <<= 1) rs[r] += __shfl_xor(rs[r], d);
    }

    // head-contiguous output: out[(b*2048+l)*1024 + h*64 + d] — full 128B lines per block
#pragma unroll
    for (int r = 0; r < 4; r++) {
        float inv = 1.0f / rs[r];
        int l = l0 + wave * 16 + quad * 4 + r;
#pragma unroll
        for (int nt = 0; nt < 4; nt++) {
            int d = nt * 16 + l16;
            out[((long)(b * 2048 + l)) * 1024 + h * 64 + d] = f2bf(acc_o[nt][r] * inv);
        }
    }
}

// ---------------- residual + layernorm ----------------
template <int AIN_BF16, int OUT_F32>
__global__ __launch_bounds__(256) void resid_ln_k(const void* __restrict__ ap,
                                                  const unsigned short* __restrict__ rb,
                                                  const float* __restrict__ g,
                                                  const float* __restrict__ bb,
                                                  float* __restrict__ outf,
                                                  unsigned short* __restrict__ outb) {
    long row = blockIdx.x;
    int tid = threadIdx.x;
    float x0, x1, x2, x3;
    if (AIN_BF16) {
        ushort4 va = ((const ushort4*)((const unsigned short*)ap + row * 1024))[tid];
        x0 = bf2f(va.x); x1 = bf2f(va.y); x2 = bf2f(va.z); x3 = bf2f(va.w);
    } else {
        float4 va = ((const float4*)((const float*)ap + row * 1024))[tid];
        x0 = va.x; x1 = va.y; x2 = va.z; x3 = va.w;
    }
    ushort4 vr = ((const ushort4*)(rb + row * 1024))[tid];
    x0 += bf2f(vr.x); x1 += bf2f(vr.y); x2 += bf2f(vr.z); x3 += bf2f(vr.w);
    float s = x0 + x1 + x2 + x3;
    float sq = x0 * x0 + x1 * x1 + x2 * x2 + x3 * x3;
#pragma unroll
    for (int d = 1; d < 64; d <<= 1) { s += __shfl_xor(s, d); sq += __shfl_xor(sq, d); }
    __shared__ float ss[4], ssq[4];
    int wave = tid >> 6, lane = tid & 63;
    if (lane == 0) { ss[wave] = s; ssq[wave] = sq; }
    __syncthreads();
    s = ss[0] + ss[1] + ss[2] + ss[3];
    sq = ssq[0] + ssq[1] + ssq[2] + ssq[3];
    float mean = s * (1.0f / 1024.0f);
    float var = sq * (1.0f / 1024.0f) - mean * mean;
    float rstd = rsqrtf(var + 1e-5f);
    float4 vg = ((const float4*)g)[tid];
    float4 vb = ((const float4*)bb)[tid];
    float y0 = (x0 - mean) * rstd * vg.x + vb.x;
    float y1 = (x1 - mean) * rstd * vg.y + vb.y;
    float y2 = (x2 - mean) * rstd * vg.z + vb.z;
    float y3 = (x3 - mean) * rstd * vg.w + vb.w;
    if (OUT_F32) {
        float4 o; o.x = y0; o.y = y1; o.z = y2; o.w = y3;
        ((float4*)(outf + row * 1024))[tid] = o;
    } else {
        ushort4 ob; ob.x = f2bf(y0); ob.y = f2bf(y1); ob.z = f2bf(y2); ob.w = f2bf(y3);
        ((ushort4*)(outb + row * 1024))[tid] = ob;
    }
}

extern "C" void kernel_launch(void* const* d_in, const int* in_sizes, int n_in,
                              void* d_out, int out_size, void* d_ws, size_t ws_size,
                              hipStream_t stream) {
    const float* x    = (const float*)d_in[0];
    const float* enc  = (const float*)d_in[1];
    const int*   mask = (const int*)d_in[2];
    const float* q1W  = (const float*)d_in[3];
    const float* w1W  = (const float*)d_in[4];
    const float* o1W  = (const float*)d_in[5];
    const float* q2W  = (const float*)d_in[6];
    const float* w2W  = (const float*)d_in[7];
    const float* o2W  = (const float*)d_in[8];
    const float* ffW1 = (const float*)d_in[9];
    const float* ffb1 = (const float*)d_in[10];
    const float* ffW2 = (const float*)d_in[11];
    const float* ffb2 = (const float*)d_in[12];
    const float* g1 = (const float*)d_in[13];
    const float* b1 = (const float*)d_in[14];
    const float* g2 = (const float*)d_in[15];
    const float* b2 = (const float*)d_in[16];
    const float* g3 = (const float*)d_in[17];
    const float* b3 = (const float*)d_in[18];
    float* outp = (float*)d_out;

    const int T = 4096;   // B*L
    const int D = 1024;
    const int F = 4096;   // MLP

    char* ws = (char*)d_ws;
    auto alloc = [&](size_t sz) { char* p = ws; ws += (sz + 255) & ~(size_t)255; return p; };
    unsigned short* qw1Wt = (unsigned short*)alloc((size_t)2 * D * D * 2); // fused [2048][1024]
    unsigned short* o1Wt  = (unsigned short*)alloc((size_t)D * D * 2);
    unsigned short* q2Wt  = (unsigned short*)alloc((size_t)D * D * 2);
    unsigned short* w2Wt  = (unsigned short*)alloc((size_t)D * D * 2);
    unsigned short* o2Wt  = (unsigned short*)alloc((size_t)D * D * 2);
    unsigned short* ffW1t = (unsigned short*)alloc((size_t)F * D * 2);
    unsigned short* ffW2t = (unsigned short*)alloc((size_t)D * F * 2);
    unsigned short* xb    = (unsigned short*)alloc((size_t)T * D * 2);
    unsigned short* encb  = (unsigned short*)alloc((size_t)T * D * 2);
    unsigned short* Qhb   = (unsigned short*)alloc((size_t)T * D * 2);
    unsigned short* Khb   = (unsigned short*)alloc((size_t)T * D * 2);
    unsigned short* KhTb  = (unsigned short*)alloc((size_t)T * D * 2);
    unsigned short* attnb = (unsigned short*)alloc((size_t)T * D * 2);
    float*          mask4b= (float*)alloc((size_t)8192 * 4);
    unsigned short* projb = (unsigned short*)alloc((size_t)T * D * 2);
    unsigned short* x1s   = (unsigned short*)alloc((size_t)T * D * 2);
    unsigned short* x2s   = (unsigned short*)alloc((size_t)T * D * 2);
    unsigned short* S1    = (unsigned short*)alloc((size_t)T * F * 2); // 32 MB scratch
    unsigned short* hb    = S1;                 // [4096][4096]

    dim3 blk256(256);
    dim3 blk512(512);
    dim3 tblk(32, 8);

    // prologue: fused casts (+ mask4 prep) + fused weight transposes
    cast2_bf16_k<<<dim3(T * D / 4 / 256, 3), blk256, 0, stream>>>(x, xb, enc, encb, T * D / 4, mask, mask4b);
    transpose_all_k<<<dim3(14336), tblk, 0, stream>>>(
        q1W, w1W, o1W, q2W, w2W, o2W, ffW1, ffW2,
        qw1Wt, qw1Wt + (size_t)D * D, o1Wt, q2Wt, w2Wt, o2Wt, ffW1t, ffW2t);

    // ---- self attention ----
    // qkv GEMM with fused head-split epilogue: writes Qhb, Khb, KhTb directly
    gemm8_k<7><<<dim3(2 * D / 128, T / 128, 1), blk512, 0, stream>>>(
        xb, qw1Wt, nullptr, nullptr, nullptr, nullptr, Qhb, Khb, KhTb, T, 2 * D, D);
    flash_attn11_k<0><<<dim3(32, 32), blk256, 0, stream>>>(Qhb, Khb, KhTb, nullptr, attnb);
    gemm8_k<4><<<dim3(D / 128, T / 128, 1), blk512, 0, stream>>>(
        attnb, o1Wt, projb, nullptr, nullptr, nullptr, nullptr, nullptr, nullptr, T, D, D);
    resid_ln_k<0, 0><<<dim3(T), blk256, 0, stream>>>(x, projb, g1, b1, nullptr, x1s);

    // ---- cross attention ----
    // q2 (z=0) -> Qhb head-split; w2 (z=1) -> Khb + KhTb
    gemm8_k<8><<<dim3(D / 128, T / 128, 2), blk512, 0, stream>>>(
        x1s, q2Wt, nullptr, nullptr, encb, w2Wt, Qhb, Khb, KhTb, T, D, D);
    flash_attn11_k<1><<<dim3(32, 32), blk256, 0, stream>>>(Qhb, Khb, KhTb, mask4b, attnb);
    gemm8_k<4><<<dim3(D / 128, T / 128, 1), blk512, 0, stream>>>(
        attnb, o2Wt, projb, nullptr, nullptr, nullptr, nullptr, nullptr, nullptr, T, D, D);
    resid_ln_k<1, 0><<<dim3(T), blk256, 0, stream>>>(x1s, projb, g2, b2, nullptr, x2s);

    // ---- feed forward ----
    gemm_k<2, 128><<<dim3(F / 128, T / 128, 1), blk256, 0, stream>>>(
        x2s, ffW1t, hb, ffb1, T, F, D);
    gemm8_k<6><<<dim3(D / 128, T / 128, 1), blk512, 0, stream>>>(
        hb, ffW2t, projb, ffb2, nullptr, nullptr, nullptr, nullptr, nullptr, T, D, F);
    resid_ln_k<1, 1><<<dim3(T), blk256, 0, stream>>>(x2s, projb, g3, b3, outp, nullptr);
}

// Round 9
// 463.742 us; speedup vs baseline: 1.1359x; 1.0408x over previous
//
#include <hip/hip_runtime.h>
#include <hip/hip_bf16.h>
#include <math.h>
#include <stdint.h>

typedef __attribute__((ext_vector_type(8))) short bf16x8_t;
typedef __attribute__((ext_vector_type(4))) float f32x4_t;

#define LOG2E 1.4426950408889634f
#define GLB(p) ((const __attribute__((address_space(1))) void*)(p))
#define LDS(p) ((__attribute__((address_space(3))) void*)(p))

__device__ __forceinline__ unsigned short f2bf(float f) {
    union { float f; unsigned int u; } v; v.f = f;
    unsigned int r = v.u + 0x7FFFu + ((v.u >> 16) & 1u);
    return (unsigned short)(r >> 16);
}

__device__ __forceinline__ float bf2f(unsigned short us) {
    union { unsigned int u; float f; } c; c.u = (unsigned int)us << 16; return c.f;
}

__device__ __forceinline__ unsigned int pack2bf(float a, float b) {
#if __has_builtin(__builtin_amdgcn_cvt_pk_bf16_f32)
    auto r = __builtin_amdgcn_cvt_pk_bf16_f32(a, b);
    unsigned int u;
    __builtin_memcpy(&u, &r, 4);
    return u;
#else
    return (unsigned int)f2bf(a) | ((unsigned int)f2bf(b) << 16);
#endif
}

__device__ __forceinline__ float fast_rcp(float x) {
#if __has_builtin(__builtin_amdgcn_rcpf)
    return __builtin_amdgcn_rcpf(x);
#else
    return 1.0f / x;
#endif
}

// single-instruction v_exp_f32 (bypasses OCML denorm-fixup path)
__device__ __forceinline__ float fexp2(float x) {
#if __has_builtin(__builtin_amdgcn_exp2f)
    return __builtin_amdgcn_exp2f(x);
#else
    return exp2f(x);
#endif
}

// gelu tanh-form: 0.5x(1+tanh(0.79788456(x+0.044715x^3))) = x*t/(t+1), t=e^{2 inner}
__device__ __forceinline__ float gelu_fast(float v) {
    float x2 = v * v;
    float inner = v * fmaf(0.0356774081f, x2, 0.7978845608f);
    inner = fminf(fmaxf(inner, -20.f), 20.f);
    float t = fexp2(inner * 2.8853900817779268f); // 2*log2(e)
    return v * t * fast_rcp(t + 1.0f);
}

// ---------------- fused cast fp32 -> bf16 for x, enc + mask4 prep ----------------
// mask4[b][t][l16][nt] = maskp[b*2048 + t*64 + nt*16 + l16] ? -1e10 : 0  (8192 floats)
__global__ void cast2_bf16_k(const float* __restrict__ inA, unsigned short* __restrict__ outA,
                             const float* __restrict__ inB, unsigned short* __restrict__ outB,
                             int n4, const int* __restrict__ maskp, float* __restrict__ mask4) {
    if (blockIdx.y == 2) {
        int i = blockIdx.x * blockDim.x + threadIdx.x;
        if (i < 8192) {
            int nt = i & 3, l16 = (i >> 2) & 15, t = (i >> 6) & 31, b = (i >> 11) & 1;
            mask4[i] = maskp[b * 2048 + t * 64 + nt * 16 + l16] ? -1e10f : 0.0f;
        }
        return;
    }
    const float* in = blockIdx.y ? inB : inA;
    unsigned short* out = blockIdx.y ? outB : outA;
    int i = blockIdx.x * blockDim.x + threadIdx.x;
    if (i < n4) {
        float4 v = ((const float4*)in)[i];
        ushort4 o;
        o.x = f2bf(v.x); o.y = f2bf(v.y); o.z = f2bf(v.z); o.w = f2bf(v.w);
        ((ushort4*)out)[i] = o;
    }
}

// ---------------- fused weight transpose+cast: all 8 weights in one dispatch ----------------
// o1W (which==2) and o2W (which==5) get a K-permutation: Wt[n][h*64+d] = W[d*16+h][n]
// (matches flash attn's head-contiguous output layout; permuted READ rows, coalesced writes)
__global__ void transpose_all_k(const float* __restrict__ s0, const float* __restrict__ s1,
                                const float* __restrict__ s2, const float* __restrict__ s3,
                                const float* __restrict__ s4, const float* __restrict__ s5,
                                const float* __restrict__ s6, const float* __restrict__ s7,
                                unsigned short* __restrict__ d0, unsigned short* __restrict__ d1,
                                unsigned short* __restrict__ d2, unsigned short* __restrict__ d3,
                                unsigned short* __restrict__ d4, unsigned short* __restrict__ d5,
                                unsigned short* __restrict__ d6, unsigned short* __restrict__ d7) {
    __shared__ float tile[32][33];
    int idx = blockIdx.x;
    const float* W; unsigned short* Wt; int K, N, bx, by;
    bool permK = false;
    if (idx < 6144) {
        int which = idx >> 10, t = idx & 1023;
        bx = t & 31; by = t >> 5; K = 1024; N = 1024;
        switch (which) {
            case 0: W = s0; Wt = d0; break;
            case 1: W = s1; Wt = d1; break;
            case 2: W = s2; Wt = d2; permK = true; break;
            case 3: W = s3; Wt = d3; break;
            case 4: W = s4; Wt = d4; break;
            default: W = s5; Wt = d5; permK = true; break;
        }
    } else if (idx < 10240) {
        int t = idx - 6144;
        bx = t & 127; by = t >> 7; K = 1024; N = 4096;
        W = s6; Wt = d6;
    } else {
        int t = idx - 10240;
        bx = t & 31; by = t >> 5; K = 4096; N = 1024;
        W = s7; Wt = d7;
    }
    int k0 = by * 32, n0 = bx * 32;
    int tx = threadIdx.x, ty = threadIdx.y; // 32 x 8
#pragma unroll
    for (int i = 0; i < 32; i += 8) {
        int kr = k0 + ty + i;
        int srcr = permK ? ((kr & 63) * 16 + (kr >> 6)) : kr;  // invperm: k'=h*64+d -> d*16+h
        tile[ty + i][tx] = W[(long)srcr * N + n0 + tx];
    }
    __syncthreads();
#pragma unroll
    for (int i = 0; i < 32; i += 8)
        Wt[(long)(n0 + ty + i) * K + k0 + tx] = f2bf(tile[tx][ty + i]);
}

// ---------------- GEMM8 (512 thr): 128x128 tile, dbuf + counted vmcnt (T3+T4) ----------
// 8 waves (2M x 4N), wave tile 64x32, acc 4x2, LDS 64KB (2 blocks/CU).
// EP: 2 = bias+gelu -> bf16, 4 = bf16, 6 = bias -> bf16,
//     7 = self-attn QK proj: cols [0,1024) -> Q head-split, [1024,2048) -> K + K^T perm
//     8 = cross-attn: z=0 -> Q head-split, z=1 -> K + K^T perm
template <int EP>
__global__ __launch_bounds__(512, 4) void gemm8_k(const unsigned short* __restrict__ A,
                                                  const unsigned short* __restrict__ Bt,
                                                  void* __restrict__ outp,
                                                  const float* __restrict__ bias,
                                                  const unsigned short* __restrict__ A2,
                                                  const unsigned short* __restrict__ Bt2,
                                                  unsigned short* __restrict__ qout,
                                                  unsigned short* __restrict__ kout,
                                                  unsigned short* __restrict__ ktout,
                                                  int M, int N, int K) {
    if (blockIdx.z) { A = A2; Bt = Bt2; }
    __shared__ __align__(16) unsigned short SMEM[32768]; // 64KB: As | Bs, reused as Ct
    unsigned short* As = SMEM;
    unsigned short* Bs = SMEM + 16384;
    int tid = threadIdx.x;
    int wave = tid >> 6, lane = tid & 63;
    int wm = wave >> 2, wn = wave & 3;   // 2 x 4 wave grid; wave tile 64 x 32
    int quad = lane >> 4, l16 = lane & 15;
    int bm = blockIdx.y * 128, bn = blockIdx.x * 128;

    f32x4_t acc[4][2] = {};

    int srow = tid >> 3;                 // 0..63
    int sgrp = (tid & 7) ^ (srow & 7);
    const unsigned short* Ag[2];
    const unsigned short* Bg[2];
#pragma unroll
    for (int i = 0; i < 2; i++) {
        Ag[i] = A + (long)(bm + i * 64 + srow) * K + sgrp * 8;
        Bg[i] = Bt + (long)(bn + i * 64 + srow) * K + sgrp * 8;
    }

    auto stage = [&](int buf, int k0) {
#pragma unroll
        for (int i = 0; i < 2; i++)
            __builtin_amdgcn_global_load_lds(GLB(Ag[i] + k0), LDS(As + buf * 8192 + i * 4096 + tid * 8), 16, 0, 0);
#pragma unroll
        for (int i = 0; i < 2; i++)
            __builtin_amdgcn_global_load_lds(GLB(Bg[i] + k0), LDS(Bs + buf * 8192 + i * 4096 + tid * 8), 16, 0, 0);
    };

    auto compute = [&](int buf) {
        const unsigned short* Ab = As + buf * 8192;
        const unsigned short* Bb = Bs + buf * 8192;
#pragma unroll
        for (int kk = 0; kk < 2; kk++) {
            int xg = ((kk * 4 + quad) ^ (l16 & 7)) * 8;
            bf16x8_t af[4], bfr[2];
#pragma unroll
            for (int t = 0; t < 4; t++)
                af[t] = *(const bf16x8_t*)(Ab + (wm * 64 + t * 16 + l16) * 64 + xg);
#pragma unroll
            for (int t = 0; t < 2; t++)
                bfr[t] = *(const bf16x8_t*)(Bb + (wn * 32 + t * 16 + l16) * 64 + xg);
#pragma unroll
            for (int mt = 0; mt < 4; mt++)
#pragma unroll
                for (int nt = 0; nt < 2; nt++)
                    acc[mt][nt] = __builtin_amdgcn_mfma_f32_16x16x32_bf16(af[mt], bfr[nt], acc[mt][nt], 0, 0, 0);
        }
    };

    stage(0, 0);
    const int NS = K >> 6;
    for (int i = 0; i < NS; i++) {
        if (i + 1 < NS) {
            stage((i + 1) & 1, (i + 1) << 6);  // next tile's 4 loads stay in flight
            asm volatile("s_waitcnt vmcnt(4)\n\ts_barrier" ::: "memory");
        } else {
            asm volatile("s_waitcnt vmcnt(0)\n\ts_barrier" ::: "memory");
        }
        compute(i & 1);
        asm volatile("s_barrier" ::: "memory");  // readers done before restage of this buf
    }

    if (EP == 7 || EP == 8) {
        // ---- fused head-split epilogue (replaces split_qk_k / transpose_heads_perm_k) ----
        bool kmode = (EP == 7) ? (bn >= 1024) : (blockIdx.z != 0);
        int G = (EP == 7 && kmode) ? ((bn - 1024) >> 7) : (bn >> 7);  // d-group 0..7
        unsigned short* Ct = SMEM;            // [128][132] bf16 output tile (33792B)
#pragma unroll
        for (int mt = 0; mt < 4; mt++)
#pragma unroll
            for (int nt = 0; nt < 2; nt++)
#pragma unroll
                for (int r = 0; r < 4; r++) {
                    int rr = wm * 64 + mt * 16 + quad * 4 + r;
                    int cc = wn * 32 + nt * 16 + l16;
                    Ct[rr * 132 + cc] = f2bf(acc[mt][nt][r]);
                }
        __syncthreads();
        int bq = bm >> 11;                    // batch (tiles never straddle 2048)
        if (!kmode) {
            // Q head-split: Qh[(b*16+h)][ll][ (G^sw)*8 + j ] = C[ll][(G*8+j)*16 + h]
#pragma unroll
            for (int i = 0; i < 4; i++) {
                int e = tid + i * 512;        // 2048 = 128 rows x 16 heads
                int h = e & 15, rl = e >> 4;
                int ll = (bm & 2047) + rl;
                union { uint4 v; unsigned short s[8]; } u;
#pragma unroll
                for (int j = 0; j < 8; j++) u.s[j] = Ct[rl * 132 + j * 16 + h];
                *(uint4*)(qout + (((long)(bq * 16 + h) * 2048 + ll) << 6) + ((G ^ (ll & 7)) << 3)) = u.v;
            }
        } else {
            // K head-split (same gather as Q)
#pragma unroll
            for (int i = 0; i < 4; i++) {
                int e = tid + i * 512;
                int h = e & 15, rl = e >> 4;
                int mm = (bm & 2047) + rl;
                union { uint4 v; unsigned short s[8]; } u;
#pragma unroll
                for (int j = 0; j < 8; j++) u.s[j] = Ct[rl * 132 + j * 16 + h];
                *(uint4*)(kout + (((long)(bq * 16 + h) * 2048 + mm) << 6) + ((G ^ (mm & 7)) << 3)) = u.v;
            }
            // K^T + m-perm: KhT[(b*16+h)*64+d][m0 + (glog^(d&7))*8 + j] = K[m0 + (p>>2)+(p&3)*16][d]
#pragma unroll
            for (int i = 0; i < 4; i++) {
                int e = tid + i * 512;        // 2048 = 16h x 8dl x 2m0s x 8glog
                int glog = e & 7, m0s = (e >> 3) & 1, dl = (e >> 4) & 7, h = e >> 7;
                int d = G * 8 + dl;
                union { uint4 v; unsigned short s[8]; } u;
#pragma unroll
                for (int j = 0; j < 8; j++) {
                    int p = glog * 8 + j;
                    int ml = (p >> 2) + (p & 3) * 16;
                    u.s[j] = Ct[(m0s * 64 + ml) * 132 + dl * 16 + h];
                }
                int mmbase = (bm & 2047) + m0s * 64;
                int gph = glog ^ (d & 7);
                *(uint4*)(ktout + ((long)(bq * 16 + h) * 64 + d) * 2048 + mmbase + gph * 8) = u.v;
            }
        }
        return;
    }

#pragma unroll
    for (int mt = 0; mt < 4; mt++)
#pragma unroll
        for (int nt = 0; nt < 2; nt++)
#pragma unroll
            for (int r = 0; r < 4; r++) {
                int gm = bm + wm * 64 + mt * 16 + quad * 4 + r;
                int gn = bn + wn * 32 + nt * 16 + l16;
                float v = acc[mt][nt][r];
                if (EP == 2) {
                    v = gelu_fast(v + bias[gn]);
                    ((unsigned short*)outp)[(long)gm * N + gn] = f2bf(v);
                } else if (EP == 6) {
                    ((unsigned short*)outp)[(long)gm * N + gn] = f2bf(v + bias[gn]);
                } else {
                    ((unsigned short*)outp)[(long)gm * N + gn] = f2bf(v);
                }
            }
}

// ---------------- flash attention v11: XCD bh-grouping + head-contiguous output ----------
// Each XCD owns 4 whole heads (bh) x all 32 l-tiles -> K stream L2-resident (~12MB fetch).
// Output layout [b][l][h*64+d]: each block writes its own FULL 128B lines (contiguous
// 64 shorts per row) -> no cross-block write merging needed, no partial-line writeback.
// o1Wt/o2Wt rows are permuted to match (see transpose_all_k permK).
template <int USE_MASK>
__global__ __launch_bounds__(256, 4) void flash_attn11_k(const unsigned short* __restrict__ Qh,
                                                         const unsigned short* __restrict__ Kh,
                                                         const unsigned short* __restrict__ KhTp,
                                                         const float* __restrict__ mask4,
                                                         unsigned short* __restrict__ out) {
    __shared__ __align__(16) unsigned short K1[64 * 64]; // [m][d] swizzled groups
    __shared__ __align__(16) unsigned short K2[64 * 64]; // [d][p] swizzled groups
    __shared__ __align__(16) unsigned short Ps[64 * 64]; // [l][p] XOR-8 row-swizzled
    __shared__ __align__(16) float Ml[USE_MASK ? 2048 : 4];

    int tid = threadIdx.x;
    int wave = tid >> 6, lane = tid & 63;
    int quad = lane >> 4, l16 = lane & 15;
    // XCD swizzle: group all l-tiles of a head onto one XCD
    int o = blockIdx.y * 32 + blockIdx.x;
    int bh = (o & 7) + ((o >> 8) << 3);
    int l0 = ((o >> 3) & 31) << 6;
    int b = bh >> 4, h = bh & 15;
    const unsigned short* k1p = Kh + (long)bh * 2048 * 64 + tid * 8;
    const unsigned short* k2p = KhTp + (long)bh * 64 * 2048 + (long)(tid >> 3) * 2048 + (tid & 7) * 8;

    int sw = l16 & 7;

    // Q fragments live in registers for the whole kernel (wave-invariant rows)
    const unsigned short* qrow = Qh + ((long)bh * 2048 + l0 + wave * 16 + l16) * 64;
    bf16x8_t qf[2];
#pragma unroll
    for (int kk = 0; kk < 2; kk++)
        qf[kk] = *(const bf16x8_t*)(qrow + ((kk * 4 + quad) ^ sw) * 8);

    // tile 0 staged via global_load_lds; __syncthreads drains it (once)
    __builtin_amdgcn_global_load_lds(GLB(k1p), LDS(K1 + tid * 8), 16, 0, 0);
    __builtin_amdgcn_global_load_lds(GLB(k1p + 2048), LDS(K1 + tid * 8 + 2048), 16, 0, 0);
    __builtin_amdgcn_global_load_lds(GLB(k2p), LDS(K2 + tid * 8), 16, 0, 0);
    __builtin_amdgcn_global_load_lds(GLB(k2p + 32 * 2048), LDS(K2 + tid * 8 + 2048), 16, 0, 0);
    if (USE_MASK) {
        const float* mp = mask4 + b * 2048;
        for (int c = tid; c < 512; c += 256)
            ((float4*)Ml)[c] = ((const float4*)mp)[c];
    }
    __syncthreads();

    const float C1 = 0.125f * LOG2E;
    f32x4_t acc_o[4] = {};
    float rs[4] = {0.f, 0.f, 0.f, 0.f};

    for (int t = 0; t < 32; ++t) {
        // T14 issue-early: next tile -> registers; latency hides under this tile's compute
        uint4 rA, rB, rC, rD;
        if (t < 31) {
            k1p += 4096;
            k2p += 64;
            rA = *(const uint4*)(k1p);
            rB = *(const uint4*)(k1p + 2048);
            rC = *(const uint4*)(k2p);
            rD = *(const uint4*)(k2p + 32 * 2048);
        }

        float4 mq = make_float4(0.f, 0.f, 0.f, 0.f);
        if (USE_MASK) mq = *(const float4*)(Ml + t * 64 + l16 * 4);

        // S = Q @ Ktile^T : wave handles 16 Q rows (band = wave*16), 64 m cols
        f32x4_t sacc[4] = {};
        __builtin_amdgcn_s_setprio(1);
#pragma unroll
        for (int kk = 0; kk < 2; kk++) {
            int xg = ((kk * 4 + quad) ^ sw) * 8;
#pragma unroll
            for (int nt = 0; nt < 4; nt++) {
                bf16x8_t bfr = *(const bf16x8_t*)(K1 + (nt * 16 + l16) * 64 + xg);
                sacc[nt] = __builtin_amdgcn_mfma_f32_16x16x32_bf16(qf[kk], bfr, sacc[nt], 0, 0, 0);
            }
        }
        __builtin_amdgcn_s_setprio(0);

        // p = exp2(s*C1 + mf); per-lane row-sum; write P 8B (4 bf16, permuted cols, swizzled)
#pragma unroll
        for (int r = 0; r < 4; r++) {
            float p0 = fexp2(fmaf(sacc[0][r], C1, mq.x));
            float p1 = fexp2(fmaf(sacc[1][r], C1, mq.y));
            float p2 = fexp2(fmaf(sacc[2][r], C1, mq.z));
            float p3 = fexp2(fmaf(sacc[3][r], C1, mq.w));
            rs[r] += (p0 + p1) + (p2 + p3);
            uint2 pk; pk.x = pack2bf(p0, p1); pk.y = pack2bf(p2, p3);
            int Rrow = wave * 16 + quad * 4 + r;
            int grp = (l16 >> 1) ^ (Rrow & 7);
            *(uint2*)(Ps + Rrow * 64 + grp * 8 + (l16 & 1) * 4) = pk;
        }

        // O += P @ Ktile : A = own band of Ps (wave-local, no barrier needed), B = K2
        __builtin_amdgcn_s_setprio(1);
#pragma unroll
        for (int kk = 0; kk < 2; kk++) {
            int xg = ((kk * 4 + quad) ^ sw) * 8;
            int Rr = wave * 16 + l16;
            int pg = ((kk * 4 + quad) ^ (l16 & 7)) * 8;
            bf16x8_t af = *(const bf16x8_t*)(Ps + Rr * 64 + pg);
#pragma unroll
            for (int nt = 0; nt < 4; nt++) {
                bf16x8_t bfr = *(const bf16x8_t*)(K2 + (nt * 16 + l16) * 64 + xg);
                acc_o[nt] = __builtin_amdgcn_mfma_f32_16x16x32_bf16(af, bfr, acc_o[nt], 0, 0, 0);
            }
        }
        __builtin_amdgcn_s_setprio(0);

        // write-late: all waves done reading K1/K2, then land the prefetched tile
        asm volatile("s_barrier" ::: "memory");
        if (t < 31) {
            *(uint4*)(K1 + tid * 8) = rA;            // compiler inserts vmcnt waits here
            *(uint4*)(K1 + tid * 8 + 2048) = rB;
            *(uint4*)(K2 + tid * 8) = rC;
            *(uint4*)(K2 + tid * 8 + 2048) = rD;
            asm volatile("s_waitcnt lgkmcnt(0)\n\ts_barrier" ::: "memory");
        }
    }

    // single final reduction of row sums across the 16 l16 lanes
#pragma unroll
    for (int r = 0; r < 4; r++) {
#pragma unroll
        for (int d = 1; d < 16; d <<= 1) rs[r] += __shfl_xor(rs[r], d);
    }

    // head-contiguous output: out[(b*2048+l)*1024 + h*64 + d] — full 128B lines per block
#pragma unroll
    for (int r = 0; r < 4; r++) {
        float inv = 1.0f / rs[r];
        int l = l0 + wave * 16 + quad * 4 + r;
#pragma unroll
        for (int nt = 0; nt < 4; nt++) {
            int d = nt * 16 + l16;
            out[((long)(b * 2048 + l)) * 1024 + h * 64 + d] = f2bf(acc_o[nt][r] * inv);
        }
    }
}

// ---------------- residual + layernorm ----------------
template <int AIN_BF16, int OUT_F32>
__global__ __launch_bounds__(256) void resid_ln_k(const void* __restrict__ ap,
                                                  const unsigned short* __restrict__ rb,
                                                  const float* __restrict__ g,
                                                  const float* __restrict__ bb,
                                                  float* __restrict__ outf,
                                                  unsigned short* __restrict__ outb) {
    long row = blockIdx.x;
    int tid = threadIdx.x;
    float x0, x1, x2, x3;
    if (AIN_BF16) {
        ushort4 va = ((const ushort4*)((const unsigned short*)ap + row * 1024))[tid];
        x0 = bf2f(va.x); x1 = bf2f(va.y); x2 = bf2f(va.z); x3 = bf2f(va.w);
    } else {
        float4 va = ((const float4*)((const float*)ap + row * 1024))[tid];
        x0 = va.x; x1 = va.y; x2 = va.z; x3 = va.w;
    }
    ushort4 vr = ((const ushort4*)(rb + row * 1024))[tid];
    x0 += bf2f(vr.x); x1 += bf2f(vr.y); x2 += bf2f(vr.z); x3 += bf2f(vr.w);
    float s = x0 + x1 + x2 + x3;
    float sq = x0 * x0 + x1 * x1 + x2 * x2 + x3 * x3;
#pragma unroll
    for (int d = 1; d < 64; d <<= 1) { s += __shfl_xor(s, d); sq += __shfl_xor(sq, d); }
    __shared__ float ss[4], ssq[4];
    int wave = tid >> 6, lane = tid & 63;
    if (lane == 0) { ss[wave] = s; ssq[wave] = sq; }
    __syncthreads();
    s = ss[0] + ss[1] + ss[2] + ss[3];
    sq = ssq[0] + ssq[1] + ssq[2] + ssq[3];
    float mean = s * (1.0f / 1024.0f);
    float var = sq * (1.0f / 1024.0f) - mean * mean;
    float rstd = rsqrtf(var + 1e-5f);
    float4 vg = ((const float4*)g)[tid];
    float4 vb = ((const float4*)bb)[tid];
    float y0 = (x0 - mean) * rstd * vg.x + vb.x;
    float y1 = (x1 - mean) * rstd * vg.y + vb.y;
    float y2 = (x2 - mean) * rstd * vg.z + vb.z;
    float y3 = (x3 - mean) * rstd * vg.w + vb.w;
    if (OUT_F32) {
        float4 o; o.x = y0; o.y = y1; o.z = y2; o.w = y3;
        ((float4*)(outf + row * 1024))[tid] = o;
    } else {
        ushort4 ob; ob.x = f2bf(y0); ob.y = f2bf(y1); ob.z = f2bf(y2); ob.w = f2bf(y3);
        ((ushort4*)(outb + row * 1024))[tid] = ob;
    }
}

extern "C" void kernel_launch(void* const* d_in, const int* in_sizes, int n_in,
                              void* d_out, int out_size, void* d_ws, size_t ws_size,
                              hipStream_t stream) {
    const float* x    = (const float*)d_in[0];
    const float* enc  = (const float*)d_in[1];
    const int*   mask = (const int*)d_in[2];
    const float* q1W  = (const float*)d_in[3];
    const float* w1W  = (const float*)d_in[4];
    const float* o1W  = (const float*)d_in[5];
    const float* q2W  = (const float*)d_in[6];
    const float* w2W  = (const float*)d_in[7];
    const float* o2W  = (const float*)d_in[8];
    const float* ffW1 = (const float*)d_in[9];
    const float* ffb1 = (const float*)d_in[10];
    const float* ffW2 = (const float*)d_in[11];
    const float* ffb2 = (const float*)d_in[12];
    const float* g1 = (const float*)d_in[13];
    const float* b1 = (const float*)d_in[14];
    const float* g2 = (const float*)d_in[15];
    const float* b2 = (const float*)d_in[16];
    const float* g3 = (const float*)d_in[17];
    const float* b3 = (const float*)d_in[18];
    float* outp = (float*)d_out;

    const int T = 4096;   // B*L
    const int D = 1024;
    const int F = 4096;   // MLP

    char* ws = (char*)d_ws;
    auto alloc = [&](size_t sz) { char* p = ws; ws += (sz + 255) & ~(size_t)255; return p; };
    unsigned short* qw1Wt = (unsigned short*)alloc((size_t)2 * D * D * 2); // fused [2048][1024]
    unsigned short* o1Wt  = (unsigned short*)alloc((size_t)D * D * 2);
    unsigned short* q2Wt  = (unsigned short*)alloc((size_t)D * D * 2);
    unsigned short* w2Wt  = (unsigned short*)alloc((size_t)D * D * 2);
    unsigned short* o2Wt  = (unsigned short*)alloc((size_t)D * D * 2);
    unsigned short* ffW1t = (unsigned short*)alloc((size_t)F * D * 2);
    unsigned short* ffW2t = (unsigned short*)alloc((size_t)D * F * 2);
    unsigned short* xb    = (unsigned short*)alloc((size_t)T * D * 2);
    unsigned short* encb  = (unsigned short*)alloc((size_t)T * D * 2);
    unsigned short* Qhb   = (unsigned short*)alloc((size_t)T * D * 2);
    unsigned short* Khb   = (unsigned short*)alloc((size_t)T * D * 2);
    unsigned short* KhTb  = (unsigned short*)alloc((size_t)T * D * 2);
    unsigned short* attnb = (unsigned short*)alloc((size_t)T * D * 2);
    float*          mask4b= (float*)alloc((size_t)8192 * 4);
    unsigned short* projb = (unsigned short*)alloc((size_t)T * D * 2);
    unsigned short* x1s   = (unsigned short*)alloc((size_t)T * D * 2);
    unsigned short* x2s   = (unsigned short*)alloc((size_t)T * D * 2);
    unsigned short* S1    = (unsigned short*)alloc((size_t)T * F * 2); // 32 MB scratch
    unsigned short* hb    = S1;                 // [4096][4096]

    dim3 blk256(256);
    dim3 blk512(512);
    dim3 tblk(32, 8);

    // prologue: fused casts (+ mask4 prep) + fused weight transposes
    cast2_bf16_k<<<dim3(T * D / 4 / 256, 3), blk256, 0, stream>>>(x, xb, enc, encb, T * D / 4, mask, mask4b);
    transpose_all_k<<<dim3(14336), tblk, 0, stream>>>(
        q1W, w1W, o1W, q2W, w2W, o2W, ffW1, ffW2,
        qw1Wt, qw1Wt + (size_t)D * D, o1Wt, q2Wt, w2Wt, o2Wt, ffW1t, ffW2t);

    // ---- self attention ----
    // qkv GEMM with fused head-split epilogue: writes Qhb, Khb, KhTb directly
    gemm8_k<7><<<dim3(2 * D / 128, T / 128, 1), blk512, 0, stream>>>(
        xb, qw1Wt, nullptr, nullptr, nullptr, nullptr, Qhb, Khb, KhTb, T, 2 * D, D);
    flash_attn11_k<0><<<dim3(32, 32), blk256, 0, stream>>>(Qhb, Khb, KhTb, nullptr, attnb);
    gemm8_k<4><<<dim3(D / 128, T / 128, 1), blk512, 0, stream>>>(
        attnb, o1Wt, projb, nullptr, nullptr, nullptr, nullptr, nullptr, nullptr, T, D, D);
    resid_ln_k<0, 0><<<dim3(T), blk256, 0, stream>>>(x, projb, g1, b1, nullptr, x1s);

    // ---- cross attention ----
    // q2 (z=0) -> Qhb head-split; w2 (z=1) -> Khb + KhTb
    gemm8_k<8><<<dim3(D / 128, T / 128, 2), blk512, 0, stream>>>(
        x1s, q2Wt, nullptr, nullptr, encb, w2Wt, Qhb, Khb, KhTb, T, D, D);
    flash_attn11_k<1><<<dim3(32, 32), blk256, 0, stream>>>(Qhb, Khb, KhTb, mask4b, attnb);
    gemm8_k<4><<<dim3(D / 128, T / 128, 1), blk512, 0, stream>>>(
        attnb, o2Wt, projb, nullptr, nullptr, nullptr, nullptr, nullptr, nullptr, T, D, D);
    resid_ln_k<1, 0><<<dim3(T), blk256, 0, stream>>>(x1s, projb, g2, b2, nullptr, x2s);

    // ---- feed forward ----
    gemm8_k<2><<<dim3(F / 128, T / 128, 1), blk512, 0, stream>>>(
        x2s, ffW1t, hb, ffb1, nullptr, nullptr, nullptr, nullptr, nullptr, T, F, D);
    gemm8_k<6><<<dim3(D / 128, T / 128, 1), blk512, 0, stream>>>(
        hb, ffW2t, projb, ffb2, nullptr, nullptr, nullptr, nullptr, nullptr, T, D, F);
    resid_ln_k<1, 1><<<dim3(T), blk256, 0, stream>>>(x2s, projb, g3, b3, outp, nullptr);
}